// Round 2
// baseline (8768.981 us; speedup 1.0000x reference)
//
#include <hip/hip_runtime.h>

#define B_ 16384
#define D_ 1536
#define H_ 12288
#define K_ 32

// ---------------- reduction helpers (block = 256 threads = 4 waves) ----------
__device__ __forceinline__ int blockSumI(int v, int* s4, int t) {
#pragma unroll
  for (int o = 32; o > 0; o >>= 1) v += __shfl_down(v, o, 64);
  if ((t & 63) == 0) s4[t >> 6] = v;
  __syncthreads();
  v = s4[0] + s4[1] + s4[2] + s4[3];
  __syncthreads();
  return v;
}
__device__ __forceinline__ float blockMinF(float v, float* s4, int t) {
#pragma unroll
  for (int o = 32; o > 0; o >>= 1) v = fminf(v, __shfl_down(v, o, 64));
  if ((t & 63) == 0) s4[t >> 6] = v;
  __syncthreads();
  v = fminf(fminf(s4[0], s4[1]), fminf(s4[2], s4[3]));
  __syncthreads();
  return v;
}
__device__ __forceinline__ float blockMaxF(float v, float* s4, int t) {
#pragma unroll
  for (int o = 32; o > 0; o >>= 1) v = fmaxf(v, __shfl_down(v, o, 64));
  if ((t & 63) == 0) s4[t >> 6] = v;
  __syncthreads();
  v = fmaxf(fmaxf(s4[0], s4[1]), fmaxf(s4[2], s4[3]));
  __syncthreads();
  return v;
}
__device__ __forceinline__ double blockSumD(double v, double* s4, int t) {
#pragma unroll
  for (int o = 32; o > 0; o >>= 1) v += __shfl_down(v, o, 64);
  if ((t & 63) == 0) s4[t >> 6] = v;
  __syncthreads();
  v = s4[0] + s4[1] + s4[2] + s4[3];
  __syncthreads();
  return v;
}

// ---------------- W_dec transpose: (D,H) -> (H,D) ---------------------------
__global__ __launch_bounds__(256) void transpose_wdec(const float* __restrict__ Wd,
                                                      float* __restrict__ WT) {
  __shared__ float tile[32][33];
  const int bx = blockIdx.x * 32;  // h
  const int by = blockIdx.y * 32;  // d
  const int tx = threadIdx.x;      // 0..31
  const int ty = threadIdx.y;      // 0..7
#pragma unroll
  for (int i = 0; i < 32; i += 8)
    tile[ty + i][tx] = Wd[(size_t)(by + ty + i) * H_ + bx + tx];
  __syncthreads();
#pragma unroll
  for (int i = 0; i < 32; i += 8)
    WT[(size_t)(bx + ty + i) * D_ + by + tx] = tile[tx][ty + i];
}

// ---------------- encode GEMM: pre = (x - b_dec) @ W_enc^T + b_enc ----------
#define BM 128
#define BN 128
#define BKT 16
__global__ __launch_bounds__(256) void encode_gemm(const float* __restrict__ x,
                                                   const float* __restrict__ W,
                                                   const float* __restrict__ benc,
                                                   const float* __restrict__ bdec,
                                                   float* __restrict__ out) {
  __shared__ __align__(16) float As[BKT][BM + 4];
  __shared__ __align__(16) float Bs[BKT][BN + 4];
  const int t = threadIdx.x;
  const int bm = blockIdx.x * BM;
  const int bn = blockIdx.y * BN;
  const int tx = t & 15;   // n-dir
  const int ty = t >> 4;   // m-dir

  float acc[8][8];
#pragma unroll
  for (int i = 0; i < 8; i++)
#pragma unroll
    for (int j = 0; j < 8; j++) acc[i][j] = 0.f;

  for (int k0 = 0; k0 < D_; k0 += BKT) {
    // stage A (centered x) and B (W_enc rows), transposed to [k][m]
    for (int f = t; f < 512; f += 256) {
      const int m = f >> 2;
      const int k4 = (f & 3) << 2;
      float4 xa = *(const float4*)(x + (size_t)(bm + m) * D_ + k0 + k4);
      float4 bd = *(const float4*)(bdec + k0 + k4);
      As[k4 + 0][m] = xa.x - bd.x;
      As[k4 + 1][m] = xa.y - bd.y;
      As[k4 + 2][m] = xa.z - bd.z;
      As[k4 + 3][m] = xa.w - bd.w;
      float4 wb = *(const float4*)(W + (size_t)(bn + m) * D_ + k0 + k4);
      Bs[k4 + 0][m] = wb.x;
      Bs[k4 + 1][m] = wb.y;
      Bs[k4 + 2][m] = wb.z;
      Bs[k4 + 3][m] = wb.w;
    }
    __syncthreads();
#pragma unroll
    for (int kk = 0; kk < BKT; kk++) {
      float a[8], b[8];
#pragma unroll
      for (int j = 0; j < 8; j++) a[j] = As[kk][ty * 8 + j];
#pragma unroll
      for (int j = 0; j < 8; j++) b[j] = Bs[kk][tx * 8 + j];
#pragma unroll
      for (int i = 0; i < 8; i++)
#pragma unroll
        for (int j = 0; j < 8; j++) acc[i][j] = fmaf(a[i], b[j], acc[i][j]);
    }
    __syncthreads();
  }
  // epilogue: + b_enc, float4 stores
#pragma unroll
  for (int i = 0; i < 8; i++) {
    const int gm = bm + ty * 8 + i;
    float* orow = out + (size_t)gm * H_ + bn + tx * 8;
    float4 o0, o1;
    o0.x = acc[i][0] + benc[bn + tx * 8 + 0];
    o0.y = acc[i][1] + benc[bn + tx * 8 + 1];
    o0.z = acc[i][2] + benc[bn + tx * 8 + 2];
    o0.w = acc[i][3] + benc[bn + tx * 8 + 3];
    o1.x = acc[i][4] + benc[bn + tx * 8 + 4];
    o1.y = acc[i][5] + benc[bn + tx * 8 + 5];
    o1.z = acc[i][6] + benc[bn + tx * 8 + 6];
    o1.w = acc[i][7] + benc[bn + tx * 8 + 7];
    *(float4*)(orow) = o0;
    *(float4*)(orow + 4) = o1;
  }
}

// ---------------- topk: per-row top-32 with fp64 boundary refinement --------
#define NC 128
#define DELTA2 1e-3f  // 2*delta; delta = fp32-GEMM error bound (generous)

__global__ __launch_bounds__(256) void topk_kernel(float* __restrict__ pre,
                                                   const float* __restrict__ x,
                                                   const float* __restrict__ W,
                                                   const float* __restrict__ benc,
                                                   const float* __restrict__ bdec,
                                                   float* __restrict__ ovals,
                                                   int* __restrict__ oidx) {
  const int row = blockIdx.x;
  const int t = threadIdx.x;
  float* p = pre + (size_t)row * H_;
  float4* p4 = (float4*)p;

  __shared__ int si4[4];
  __shared__ float sf4[4];
  __shared__ double sd4[4];
  __shared__ float cv[NC];
  __shared__ int ci[NC];
  __shared__ float rv[NC];
  __shared__ int ri[NC];
  __shared__ int scnt;
  __shared__ int rl[16];
  __shared__ int nrl;

  // load row: 12 float4 per thread, interleaved for coalescing
  float v[48];
#pragma unroll
  for (int i = 0; i < 12; i++) {
    float4 q = p4[i * 256 + t];
    v[i * 4 + 0] = q.x;
    v[i * 4 + 1] = q.y;
    v[i * 4 + 2] = q.z;
    v[i * 4 + 3] = q.w;
  }

  float tmin = v[0], tmax = v[0];
#pragma unroll
  for (int i = 1; i < 48; i++) {
    tmin = fminf(tmin, v[i]);
    tmax = fmaxf(tmax, v[i]);
  }
  const float gmin = blockMinF(tmin, sf4, t);
  const float gmax = blockMaxF(tmax, sf4, t);

  // binary search threshold T with count(>=T) in [36, NC]
  float lo = gmin - 1.0f, hi = gmax + 1.0f, T = lo;
  for (int it = 0; it < 40; ++it) {
    const float mid = 0.5f * (lo + hi);
    int c = 0;
#pragma unroll
    for (int i = 0; i < 48; i++) c += (v[i] >= mid) ? 1 : 0;
    c = blockSumI(c, si4, t);
    if (c >= 36 && c <= NC) { T = mid; break; }
    if (c < 36) hi = mid;
    else { lo = mid; T = mid; }
  }

  // compact candidates
  if (t == 0) scnt = 0;
  __syncthreads();
#pragma unroll
  for (int i = 0; i < 12; i++) {
#pragma unroll
    for (int j = 0; j < 4; j++) {
      const float val = v[i * 4 + j];
      if (val >= T) {
        const int pos = atomicAdd(&scnt, 1);
        if (pos < NC) {
          cv[pos] = val;
          ci[pos] = (i * 256 + t) * 4 + j;
        }
      }
    }
  }
  __syncthreads();
  int m = scnt;
  if (m > NC) m = NC;

  // rank 1: cv/ci -> rv/ri (descending, tie-break by index)
  if (t < m) {
    const float vi = cv[t];
    const int ii = ci[t];
    int r = 0;
    for (int j = 0; j < m; j++) {
      const float vj = cv[j];
      r += (vj > vi || (vj == vi && ci[j] < ii)) ? 1 : 0;
    }
    rv[r] = vi;
    ri[r] = ii;
  }
  __syncthreads();

  // boundary-uncertainty refinement in fp64
  if (t == 0) nrl = 0;
  __syncthreads();
  if (m >= 33 && t < m) {
    const float v31 = rv[31], v32 = rv[32];
    const float myv = rv[t];
    const bool band = (t <= 31) ? (myv < v32 + DELTA2) : (myv > v31 - DELTA2);
    if (band) {
      const int q = atomicAdd(&nrl, 1);
      if (q < 16) rl[q] = t;
    }
  }
  __syncthreads();
  int nr = nrl;
  if (nr > 16) nr = 16;
  for (int c = 0; c < nr; ++c) {
    const int r = rl[c];
    const int hidx = ri[r];
    const float* wrow = W + (size_t)hidx * D_;
    const float* xrow = x + (size_t)row * D_;
    double s = 0.0;
    for (int d = t; d < D_; d += 256)
      s += (double)(xrow[d] - bdec[d]) * (double)wrow[d];
    s = blockSumD(s, sd4, t);
    if (t == 0) rv[r] = (float)(s + (double)benc[hidx]);
    __syncthreads();
  }

  // rank 2 (post-refinement): rv/ri -> cv/ci
  if (t < m) {
    const float vi = rv[t];
    const int ii = ri[t];
    int r = 0;
    for (int j = 0; j < m; j++) {
      const float vj = rv[j];
      r += (vj > vi || (vj == vi && ri[j] < ii)) ? 1 : 0;
    }
    cv[r] = vi;
    ci[r] = ii;
  }
  __syncthreads();

  // zero the whole row, then scatter relu(top-32); record lists for decode
  const float4 z = make_float4(0.f, 0.f, 0.f, 0.f);
#pragma unroll
  for (int i = 0; i < 12; i++) p4[i * 256 + t] = z;
  __syncthreads();
  if (t < K_) {
    float val = 0.f;
    int id = 0;
    if (t < m) {
      id = ci[t];
      val = fmaxf(cv[t], 0.f);
      p[id] = val;
    }
    ovals[(size_t)row * K_ + t] = val;
    oidx[(size_t)row * K_ + t] = id;
  }
}

// ---------------- decode: x_hat = sparse @ W_dec^T + b_dec ------------------
__global__ __launch_bounds__(256) void decode_kernel(const float* __restrict__ vals,
                                                     const int* __restrict__ idxs,
                                                     const float* __restrict__ WT,
                                                     const float* __restrict__ Wd,
                                                     const int useT,
                                                     const float* __restrict__ bdec,
                                                     float* __restrict__ xhat) {
  const int row = blockIdx.x;
  const int t = threadIdx.x;
  __shared__ float sv[K_];
  __shared__ int si[K_];
  if (t < K_) {
    sv[t] = vals[(size_t)row * K_ + t];
    si[t] = idxs[(size_t)row * K_ + t];
  }
  __syncthreads();
  float acc[6];
#pragma unroll
  for (int j = 0; j < 6; j++) acc[j] = bdec[t + j * 256];
  for (int k = 0; k < K_; k++) {
    const float vv = sv[k];
    if (vv == 0.f) continue;  // block-uniform branch
    const int h = si[k];
    if (useT) {
      const float* wr = WT + (size_t)h * D_;
#pragma unroll
      for (int j = 0; j < 6; j++) acc[j] = fmaf(vv, wr[t + j * 256], acc[j]);
    } else {
#pragma unroll
      for (int j = 0; j < 6; j++)
        acc[j] = fmaf(vv, Wd[(size_t)(t + j * 256) * H_ + h], acc[j]);
    }
  }
  float* orow = xhat + (size_t)row * D_;
#pragma unroll
  for (int j = 0; j < 6; j++) orow[t + j * 256] = acc[j];
}

// ---------------- launch ----------------------------------------------------
extern "C" void kernel_launch(void* const* d_in, const int* in_sizes, int n_in,
                              void* d_out, int out_size, void* d_ws, size_t ws_size,
                              hipStream_t stream) {
  const float* x = (const float*)d_in[0];
  const float* Wenc = (const float*)d_in[1];
  const float* benc = (const float*)d_in[2];
  const float* Wdec = (const float*)d_in[3];
  const float* bdec = (const float*)d_in[4];

  float* out = (float*)d_out;
  float* xhat = out;                         // output 0: (B, D)
  float* pre = out + (size_t)B_ * D_;        // output 1 region doubles as pre_act

  float* wsf = (float*)d_ws;
  const size_t wt_elems = (size_t)H_ * D_;
  const size_t list_elems = (size_t)B_ * K_;
  const size_t need = (wt_elems + 2 * list_elems) * sizeof(float);
  const int useT = (ws_size >= need) ? 1 : 0;

  float* WT;
  float* vals;
  int* idxs;
  if (useT) {
    WT = wsf;
    vals = wsf + wt_elems;
    idxs = (int*)(vals + list_elems);
  } else {
    WT = nullptr;
    vals = wsf;
    idxs = (int*)(vals + list_elems);
  }

  if (useT)
    transpose_wdec<<<dim3(H_ / 32, D_ / 32), dim3(32, 8), 0, stream>>>(Wdec, WT);
  encode_gemm<<<dim3(B_ / BM, H_ / BN), 256, 0, stream>>>(x, Wenc, benc, bdec, pre);
  topk_kernel<<<B_, 256, 0, stream>>>(pre, x, Wenc, benc, bdec, vals, idxs);
  decode_kernel<<<B_, 256, 0, stream>>>(vals, idxs, WT, Wdec, useT, bdec, xhat);
}

// Round 3
// 2825.183 us; speedup vs baseline: 3.1039x; 3.1039x over previous
//
#include <hip/hip_runtime.h>

#define B_ 16384
#define D_ 1536
#define H_ 12288
#define K_ 32

typedef short bf16x8 __attribute__((ext_vector_type(8)));
typedef float f32x4 __attribute__((ext_vector_type(4)));

// ---------------- reduction helpers (block = 256 threads = 4 waves) ----------
__device__ __forceinline__ int blockSumI(int v, int* s4, int t) {
#pragma unroll
  for (int o = 32; o > 0; o >>= 1) v += __shfl_down(v, o, 64);
  if ((t & 63) == 0) s4[t >> 6] = v;
  __syncthreads();
  v = s4[0] + s4[1] + s4[2] + s4[3];
  __syncthreads();
  return v;
}
__device__ __forceinline__ float blockMinF(float v, float* s4, int t) {
#pragma unroll
  for (int o = 32; o > 0; o >>= 1) v = fminf(v, __shfl_down(v, o, 64));
  if ((t & 63) == 0) s4[t >> 6] = v;
  __syncthreads();
  v = fminf(fminf(s4[0], s4[1]), fminf(s4[2], s4[3]));
  __syncthreads();
  return v;
}
__device__ __forceinline__ float blockMaxF(float v, float* s4, int t) {
#pragma unroll
  for (int o = 32; o > 0; o >>= 1) v = fmaxf(v, __shfl_down(v, o, 64));
  if ((t & 63) == 0) s4[t >> 6] = v;
  __syncthreads();
  v = fmaxf(fmaxf(s4[0], s4[1]), fmaxf(s4[2], s4[3]));
  __syncthreads();
  return v;
}
__device__ __forceinline__ double blockSumD(double v, double* s4, int t) {
#pragma unroll
  for (int o = 32; o > 0; o >>= 1) v += __shfl_down(v, o, 64);
  if ((t & 63) == 0) s4[t >> 6] = v;
  __syncthreads();
  v = s4[0] + s4[1] + s4[2] + s4[3];
  __syncthreads();
  return v;
}

// RNE float -> bf16
__device__ __forceinline__ unsigned short f2bf(float f) {
  unsigned int u = __float_as_uint(f);
  u += 0x7fffu + ((u >> 16) & 1u);
  return (unsigned short)(u >> 16);
}

// ---------------- conversion kernels ----------------------------------------
__global__ __launch_bounds__(256) void convert_x(const float* __restrict__ x,
                                                 const float* __restrict__ bdec,
                                                 unsigned short* __restrict__ Xb) {
  const int idx = blockIdx.x * 256 + threadIdx.x;  // one float4 per thread
  const float4 v = ((const float4*)x)[idx];
  const float4 bd = ((const float4*)bdec)[idx & (D_ / 4 - 1)];  // D_/4=384 NOT pow2!
  // D_/4 = 384 is not a power of two -> use modulo properly:
  const int col4 = idx % (D_ / 4);
  const float4 b2 = ((const float4*)bdec)[col4];
  (void)bd;
  ushort4 o;
  o.x = f2bf(v.x - b2.x);
  o.y = f2bf(v.y - b2.y);
  o.z = f2bf(v.z - b2.z);
  o.w = f2bf(v.w - b2.w);
  ((ushort4*)Xb)[idx] = o;
}

__global__ __launch_bounds__(256) void convert_w(const float* __restrict__ W,
                                                 unsigned short* __restrict__ Wb) {
  const int idx = blockIdx.x * 256 + threadIdx.x;
  const float4 v = ((const float4*)W)[idx];
  ushort4 o;
  o.x = f2bf(v.x);
  o.y = f2bf(v.y);
  o.z = f2bf(v.z);
  o.w = f2bf(v.w);
  ((ushort4*)Wb)[idx] = o;
}

// ---------------- W_dec transpose: (D,H) -> (H,D) ---------------------------
__global__ __launch_bounds__(256) void transpose_wdec(const float* __restrict__ Wd,
                                                      float* __restrict__ WT) {
  __shared__ float tile[32][33];
  const int bx = blockIdx.x * 32;  // h
  const int by = blockIdx.y * 32;  // d
  const int tx = threadIdx.x;      // 0..31
  const int ty = threadIdx.y;      // 0..7
#pragma unroll
  for (int i = 0; i < 32; i += 8)
    tile[ty + i][tx] = Wd[(size_t)(by + ty + i) * H_ + bx + tx];
  __syncthreads();
#pragma unroll
  for (int i = 0; i < 32; i += 8)
    WT[(size_t)(bx + ty + i) * D_ + by + tx] = tile[tx][ty + i];
}

// ---------------- bf16 MFMA encode GEMM (m97 pattern) -----------------------
// pre[bm..][bn..] = Xb(128xK) . Wb(128xK)^T ; 128x128 tile, BK=32, 4 waves,
// each wave 64x64 = 4x4 MFMA 16x16x32 tiles.
__device__ __forceinline__ void async16(const unsigned short* g, unsigned short* l) {
  __builtin_amdgcn_global_load_lds(
      (const __attribute__((address_space(1))) unsigned int*)(const void*)g,
      (__attribute__((address_space(3))) unsigned int*)(void*)l, 16, 0, 0);
}

__global__ __launch_bounds__(256) void encode_mfma(const unsigned short* __restrict__ Xb,
                                                   const unsigned short* __restrict__ Wb,
                                                   const float* __restrict__ benc,
                                                   float* __restrict__ out) {
  __shared__ __align__(16) unsigned short As[128 * 32];
  __shared__ __align__(16) unsigned short Bs[128 * 32];
  const int t = threadIdx.x;
  const int w = t >> 6, l = t & 63;
  const int wm = w >> 1, wn = w & 1;
  const int bm = blockIdx.x * 128, bn = blockIdx.y * 128;

  f32x4 acc[4][4];
#pragma unroll
  for (int i = 0; i < 4; i++)
#pragma unroll
    for (int j = 0; j < 4; j++) acc[i][j] = (f32x4){0.f, 0.f, 0.f, 0.f};

  // staging: chunk c (16B = 8 bf16) -> row c>>2, kchunk c&3. thread t handles
  // chunks t and t+256. LDS dest = lane-ordered (wave-uniform base + lane*16).
  const int r0 = t >> 2, kc0 = (t & 3) * 8;
  const unsigned short* ga0 = Xb + (size_t)(bm + r0) * D_ + kc0;
  const unsigned short* ga1 = Xb + (size_t)(bm + r0 + 64) * D_ + kc0;
  const unsigned short* gb0 = Wb + (size_t)(bn + r0) * D_ + kc0;
  const unsigned short* gb1 = Wb + (size_t)(bn + r0 + 64) * D_ + kc0;
  unsigned short* la0 = &As[t * 8];
  unsigned short* la1 = &As[(t + 256) * 8];
  unsigned short* lb0 = &Bs[t * 8];
  unsigned short* lb1 = &Bs[(t + 256) * 8];

  const int am = l & 15;        // m/n within 16-tile
  const int aq = l >> 4;        // quad 0..3
  const int aoff = aq * 8;      // k offset of the 8-elem fragment

  for (int k0 = 0; k0 < D_; k0 += 32) {
    async16(ga0 + k0, la0);
    async16(ga1 + k0, la1);
    async16(gb0 + k0, lb0);
    async16(gb1 + k0, lb1);
    __syncthreads();  // drains vmcnt (global_load_lds) for all waves
    bf16x8 a[4], b[4];
#pragma unroll
    for (int i = 0; i < 4; i++)
      a[i] = *(const bf16x8*)&As[(wm * 64 + i * 16 + am) * 32 + aoff];
#pragma unroll
    for (int j = 0; j < 4; j++)
      b[j] = *(const bf16x8*)&Bs[(wn * 64 + j * 16 + am) * 32 + aoff];
#pragma unroll
    for (int i = 0; i < 4; i++)
#pragma unroll
      for (int j = 0; j < 4; j++)
        acc[i][j] = __builtin_amdgcn_mfma_f32_16x16x32_bf16(a[i], b[j], acc[i][j], 0, 0, 0);
    __syncthreads();
  }

  // epilogue: C/D layout col=lane&15, row=(lane>>4)*4+reg  [m89/m91]
  float bias[4];
#pragma unroll
  for (int j = 0; j < 4; j++) bias[j] = benc[bn + wn * 64 + j * 16 + am];
#pragma unroll
  for (int i = 0; i < 4; i++)
#pragma unroll
    for (int r = 0; r < 4; r++) {
      const int row = bm + wm * 64 + i * 16 + aq * 4 + r;
      float* orow = out + (size_t)row * H_ + bn + wn * 64 + am;
#pragma unroll
      for (int j = 0; j < 4; j++) orow[j * 16] = acc[i][j][r] + bias[j];
    }
}

// ---------------- fp32 fallback encode GEMM (round-2) -----------------------
#define BM 128
#define BN 128
#define BKT 16
__global__ __launch_bounds__(256) void encode_gemm(const float* __restrict__ x,
                                                   const float* __restrict__ W,
                                                   const float* __restrict__ benc,
                                                   const float* __restrict__ bdec,
                                                   float* __restrict__ out) {
  __shared__ __align__(16) float As[BKT][BM + 4];
  __shared__ __align__(16) float Bs[BKT][BN + 4];
  const int t = threadIdx.x;
  const int bm = blockIdx.x * BM;
  const int bn = blockIdx.y * BN;
  const int tx = t & 15;
  const int ty = t >> 4;

  float acc[8][8];
#pragma unroll
  for (int i = 0; i < 8; i++)
#pragma unroll
    for (int j = 0; j < 8; j++) acc[i][j] = 0.f;

  for (int k0 = 0; k0 < D_; k0 += BKT) {
    for (int f = t; f < 512; f += 256) {
      const int m = f >> 2;
      const int k4 = (f & 3) << 2;
      float4 xa = *(const float4*)(x + (size_t)(bm + m) * D_ + k0 + k4);
      float4 bd = *(const float4*)(bdec + k0 + k4);
      As[k4 + 0][m] = xa.x - bd.x;
      As[k4 + 1][m] = xa.y - bd.y;
      As[k4 + 2][m] = xa.z - bd.z;
      As[k4 + 3][m] = xa.w - bd.w;
      float4 wb = *(const float4*)(W + (size_t)(bn + m) * D_ + k0 + k4);
      Bs[k4 + 0][m] = wb.x;
      Bs[k4 + 1][m] = wb.y;
      Bs[k4 + 2][m] = wb.z;
      Bs[k4 + 3][m] = wb.w;
    }
    __syncthreads();
#pragma unroll
    for (int kk = 0; kk < BKT; kk++) {
      float a[8], b[8];
#pragma unroll
      for (int j = 0; j < 8; j++) a[j] = As[kk][ty * 8 + j];
#pragma unroll
      for (int j = 0; j < 8; j++) b[j] = Bs[kk][tx * 8 + j];
#pragma unroll
      for (int i = 0; i < 8; i++)
#pragma unroll
        for (int j = 0; j < 8; j++) acc[i][j] = fmaf(a[i], b[j], acc[i][j]);
    }
    __syncthreads();
  }
#pragma unroll
  for (int i = 0; i < 8; i++) {
    const int gm = bm + ty * 8 + i;
    float* orow = out + (size_t)gm * H_ + bn + tx * 8;
    float4 o0, o1;
    o0.x = acc[i][0] + benc[bn + tx * 8 + 0];
    o0.y = acc[i][1] + benc[bn + tx * 8 + 1];
    o0.z = acc[i][2] + benc[bn + tx * 8 + 2];
    o0.w = acc[i][3] + benc[bn + tx * 8 + 3];
    o1.x = acc[i][4] + benc[bn + tx * 8 + 4];
    o1.y = acc[i][5] + benc[bn + tx * 8 + 5];
    o1.z = acc[i][6] + benc[bn + tx * 8 + 6];
    o1.w = acc[i][7] + benc[bn + tx * 8 + 7];
    *(float4*)(orow) = o0;
    *(float4*)(orow + 4) = o1;
  }
}

// ---------------- topk: per-row top-32 with fp64 boundary refinement --------
#define NC 128

__global__ __launch_bounds__(256) void topk_kernel(float* __restrict__ pre,
                                                   const float* __restrict__ x,
                                                   const float* __restrict__ W,
                                                   const float* __restrict__ benc,
                                                   const float* __restrict__ bdec,
                                                   float* __restrict__ ovals,
                                                   int* __restrict__ oidx,
                                                   const float delta2) {
  const int row = blockIdx.x;
  const int t = threadIdx.x;
  float* p = pre + (size_t)row * H_;
  float4* p4 = (float4*)p;

  __shared__ int si4[4];
  __shared__ float sf4[4];
  __shared__ double sd4[4];
  __shared__ float cv[NC];
  __shared__ int ci[NC];
  __shared__ float rv[NC];
  __shared__ int ri[NC];
  __shared__ int scnt;
  __shared__ int rl[24];
  __shared__ int nrl;

  float v[48];
#pragma unroll
  for (int i = 0; i < 12; i++) {
    float4 q = p4[i * 256 + t];
    v[i * 4 + 0] = q.x;
    v[i * 4 + 1] = q.y;
    v[i * 4 + 2] = q.z;
    v[i * 4 + 3] = q.w;
  }

  float tmin = v[0], tmax = v[0];
#pragma unroll
  for (int i = 1; i < 48; i++) {
    tmin = fminf(tmin, v[i]);
    tmax = fmaxf(tmax, v[i]);
  }
  const float gmin = blockMinF(tmin, sf4, t);
  const float gmax = blockMaxF(tmax, sf4, t);

  // binary search threshold T with count(>=T) in [48, NC] — deep enough that
  // the captured list extends well past v32 - delta2 (band coverage).
  float lo = gmin - 1.0f, hi = gmax + 1.0f, T = lo;
  for (int it = 0; it < 40; ++it) {
    const float mid = 0.5f * (lo + hi);
    int c = 0;
#pragma unroll
    for (int i = 0; i < 48; i++) c += (v[i] >= mid) ? 1 : 0;
    c = blockSumI(c, si4, t);
    if (c >= 48 && c <= NC) { T = mid; break; }
    if (c < 48) hi = mid;
    else { lo = mid; T = mid; }
  }

  if (t == 0) scnt = 0;
  __syncthreads();
#pragma unroll
  for (int i = 0; i < 12; i++) {
#pragma unroll
    for (int j = 0; j < 4; j++) {
      const float val = v[i * 4 + j];
      if (val >= T) {
        const int pos = atomicAdd(&scnt, 1);
        if (pos < NC) {
          cv[pos] = val;
          ci[pos] = (i * 256 + t) * 4 + j;
        }
      }
    }
  }
  __syncthreads();
  int m = scnt;
  if (m > NC) m = NC;

  // rank 1
  if (t < m) {
    const float vi = cv[t];
    const int ii = ci[t];
    int r = 0;
    for (int j = 0; j < m; j++) {
      const float vj = cv[j];
      r += (vj > vi || (vj == vi && ci[j] < ii)) ? 1 : 0;
    }
    rv[r] = vi;
    ri[r] = ii;
  }
  __syncthreads();

  // fp64 refinement of all candidates within delta2 of the 31/32 boundary
  if (t == 0) nrl = 0;
  __syncthreads();
  if (m >= 33 && t < m) {
    const float v31 = rv[31], v32 = rv[32];
    const float myv = rv[t];
    const bool band = (t <= 31) ? (myv < v32 + delta2) : (myv > v31 - delta2);
    if (band) {
      const int q = atomicAdd(&nrl, 1);
      if (q < 24) rl[q] = t;
    }
  }
  __syncthreads();
  int nr = nrl;
  if (nr > 24) nr = 24;
  for (int c = 0; c < nr; ++c) {
    const int r = rl[c];
    const int hidx = ri[r];
    const float* wrow = W + (size_t)hidx * D_;
    const float* xrow = x + (size_t)row * D_;
    double s = 0.0;
    for (int d = t; d < D_; d += 256)
      s += (double)(xrow[d] - bdec[d]) * (double)wrow[d];
    s = blockSumD(s, sd4, t);
    if (t == 0) rv[r] = (float)(s + (double)benc[hidx]);
    __syncthreads();
  }

  // rank 2 (post-refinement)
  if (t < m) {
    const float vi = rv[t];
    const int ii = ri[t];
    int r = 0;
    for (int j = 0; j < m; j++) {
      const float vj = rv[j];
      r += (vj > vi || (vj == vi && ri[j] < ii)) ? 1 : 0;
    }
    cv[r] = vi;
    ci[r] = ii;
  }
  __syncthreads();

  // zero row, scatter relu(top-32), record lists
  const float4 z = make_float4(0.f, 0.f, 0.f, 0.f);
#pragma unroll
  for (int i = 0; i < 12; i++) p4[i * 256 + t] = z;
  __syncthreads();
  if (t < K_) {
    float val = 0.f;
    int id = 0;
    if (t < m) {
      id = ci[t];
      val = fmaxf(cv[t], 0.f);
      p[id] = val;
    }
    ovals[(size_t)row * K_ + t] = val;
    oidx[(size_t)row * K_ + t] = id;
  }
}

// ---------------- decode: x_hat = sparse @ W_dec^T + b_dec ------------------
__global__ __launch_bounds__(256) void decode_kernel(const float* __restrict__ vals,
                                                     const int* __restrict__ idxs,
                                                     const float* __restrict__ WT,
                                                     const float* __restrict__ Wd,
                                                     const int useT,
                                                     const float* __restrict__ bdec,
                                                     float* __restrict__ xhat) {
  const int row = blockIdx.x;
  const int t = threadIdx.x;
  __shared__ float sv[K_];
  __shared__ int si[K_];
  if (t < K_) {
    sv[t] = vals[(size_t)row * K_ + t];
    si[t] = idxs[(size_t)row * K_ + t];
  }
  __syncthreads();
  float acc[6];
#pragma unroll
  for (int j = 0; j < 6; j++) acc[j] = bdec[t + j * 256];
  for (int k = 0; k < K_; k++) {
    const float vv = sv[k];
    if (vv == 0.f) continue;
    const int h = si[k];
    if (useT) {
      const float* wr = WT + (size_t)h * D_;
#pragma unroll
      for (int j = 0; j < 6; j++) acc[j] = fmaf(vv, wr[t + j * 256], acc[j]);
    } else {
#pragma unroll
      for (int j = 0; j < 6; j++)
        acc[j] = fmaf(vv, Wd[(size_t)(t + j * 256) * H_ + h], acc[j]);
    }
  }
  float* orow = xhat + (size_t)row * D_;
#pragma unroll
  for (int j = 0; j < 6; j++) orow[t + j * 256] = acc[j];
}

// ---------------- launch ----------------------------------------------------
extern "C" void kernel_launch(void* const* d_in, const int* in_sizes, int n_in,
                              void* d_out, int out_size, void* d_ws, size_t ws_size,
                              hipStream_t stream) {
  const float* x = (const float*)d_in[0];
  const float* Wenc = (const float*)d_in[1];
  const float* benc = (const float*)d_in[2];
  const float* Wdec = (const float*)d_in[3];
  const float* bdec = (const float*)d_in[4];

  float* out = (float*)d_out;
  float* xhat = out;                   // output 0: (B, D)
  float* pre = out + (size_t)B_ * D_;  // output 1 region doubles as pre_act

  // ws layout (Tier A): WT | Xb | Wb | vals | idxs  = 160 MiB
  const size_t wt_b = (size_t)H_ * D_ * 4;       // 75.5 MB
  const size_t xb_b = (size_t)B_ * D_ * 2;       // 50.3 MB
  const size_t wb_b = (size_t)H_ * D_ * 2;       // 37.7 MB
  const size_t lst_b = (size_t)B_ * K_ * 4;      // 2.1 MB
  const size_t need_full = wt_b + xb_b + wb_b + 2 * lst_b;
  const size_t need_T = wt_b + 2 * lst_b;

  char* wsc = (char*)d_ws;
  const int bf16path = (ws_size >= need_full) ? 1 : 0;
  const int useT = (ws_size >= need_T) ? 1 : 0;

  float* WT = nullptr;
  unsigned short* Xb = nullptr;
  unsigned short* Wb = nullptr;
  float* vals;
  int* idxs;
  if (bf16path) {
    WT = (float*)wsc;
    Xb = (unsigned short*)(wsc + wt_b);
    Wb = (unsigned short*)(wsc + wt_b + xb_b);
    vals = (float*)(wsc + wt_b + xb_b + wb_b);
    idxs = (int*)(wsc + wt_b + xb_b + wb_b + lst_b);
  } else if (useT) {
    WT = (float*)wsc;
    vals = (float*)(wsc + wt_b);
    idxs = (int*)(wsc + wt_b + lst_b);
  } else {
    vals = (float*)wsc;
    idxs = (int*)(wsc + lst_b);
  }

  if (useT)
    transpose_wdec<<<dim3(H_ / 32, D_ / 32), dim3(32, 8), 0, stream>>>(Wdec, WT);

  float delta2 = 1e-3f;
  if (bf16path) {
    delta2 = 0.04f;  // 2*delta; delta covers bf16-input GEMM noise (~9 sigma)
    convert_x<<<(B_ * D_ / 4) / 256, 256, 0, stream>>>(x, bdec, Xb);
    convert_w<<<(H_ * D_ / 4) / 256, 256, 0, stream>>>(Wenc, Wb);
    encode_mfma<<<dim3(B_ / 128, H_ / 128), 256, 0, stream>>>(Xb, Wb, benc, pre);
  } else {
    encode_gemm<<<dim3(B_ / BM, H_ / BN), 256, 0, stream>>>(x, Wenc, benc, bdec, pre);
  }
  topk_kernel<<<B_, 256, 0, stream>>>(pre, x, Wenc, benc, bdec, vals, idxs, delta2);
  decode_kernel<<<B_, 256, 0, stream>>>(vals, idxs, WT, Wdec, useT, bdec, xhat);
}

// Round 4
// 2641.090 us; speedup vs baseline: 3.3202x; 1.0697x over previous
//
#include <hip/hip_runtime.h>

#define B_ 16384
#define D_ 1536
#define H_ 12288
#define K_ 32
#define CAP 1024     // candidate list capacity per row (lives in d_out scratch)
#define T0 3.0f      // candidate threshold: v32 min over rows ~3.58, margin >40 sigma
#define NC 128       // compacted candidate cap for ranking

typedef short bf16x8 __attribute__((ext_vector_type(8)));
typedef float f32x4 __attribute__((ext_vector_type(4)));

// ---------------- reduction helpers (block = 256 threads = 4 waves) ----------
__device__ __forceinline__ int blockSumI(int v, int* s4, int t) {
#pragma unroll
  for (int o = 32; o > 0; o >>= 1) v += __shfl_down(v, o, 64);
  if ((t & 63) == 0) s4[t >> 6] = v;
  __syncthreads();
  v = s4[0] + s4[1] + s4[2] + s4[3];
  __syncthreads();
  return v;
}
__device__ __forceinline__ float blockMinF(float v, float* s4, int t) {
#pragma unroll
  for (int o = 32; o > 0; o >>= 1) v = fminf(v, __shfl_down(v, o, 64));
  if ((t & 63) == 0) s4[t >> 6] = v;
  __syncthreads();
  v = fminf(fminf(s4[0], s4[1]), fminf(s4[2], s4[3]));
  __syncthreads();
  return v;
}
__device__ __forceinline__ float blockMaxF(float v, float* s4, int t) {
#pragma unroll
  for (int o = 32; o > 0; o >>= 1) v = fmaxf(v, __shfl_down(v, o, 64));
  if ((t & 63) == 0) s4[t >> 6] = v;
  __syncthreads();
  v = fmaxf(fmaxf(s4[0], s4[1]), fmaxf(s4[2], s4[3]));
  __syncthreads();
  return v;
}
__device__ __forceinline__ double blockSumD(double v, double* s4, int t) {
#pragma unroll
  for (int o = 32; o > 0; o >>= 1) v += __shfl_down(v, o, 64);
  if ((t & 63) == 0) s4[t >> 6] = v;
  __syncthreads();
  v = s4[0] + s4[1] + s4[2] + s4[3];
  __syncthreads();
  return v;
}

// RNE float -> bf16, and back
__device__ __forceinline__ unsigned short f2bf(float f) {
  unsigned int u = __float_as_uint(f);
  u += 0x7fffu + ((u >> 16) & 1u);
  return (unsigned short)(u >> 16);
}
__device__ __forceinline__ float bf2f(unsigned short s) {
  return __uint_as_float(((unsigned int)s) << 16);
}

// ---------------- small prep kernels ----------------------------------------
__global__ __launch_bounds__(256) void zero_cnt(int* __restrict__ cnt) {
  const int i = blockIdx.x * 256 + threadIdx.x;
  if (i < B_) cnt[i] = 0;
}

__global__ __launch_bounds__(256) void convert_x(const float* __restrict__ x,
                                                 const float* __restrict__ bdec,
                                                 unsigned short* __restrict__ Xb) {
  const int idx = blockIdx.x * 256 + threadIdx.x;  // one float4 per thread
  const float4 v = ((const float4*)x)[idx];
  const int col4 = idx % (D_ / 4);  // D_/4 = 384, not pow2
  const float4 b2 = ((const float4*)bdec)[col4];
  ushort4 o;
  o.x = f2bf(v.x - b2.x);
  o.y = f2bf(v.y - b2.y);
  o.z = f2bf(v.z - b2.z);
  o.w = f2bf(v.w - b2.w);
  ((ushort4*)Xb)[idx] = o;
}

__global__ __launch_bounds__(256) void convert_w(const float* __restrict__ W,
                                                 unsigned short* __restrict__ Wb) {
  const int idx = blockIdx.x * 256 + threadIdx.x;
  const float4 v = ((const float4*)W)[idx];
  ushort4 o;
  o.x = f2bf(v.x);
  o.y = f2bf(v.y);
  o.z = f2bf(v.z);
  o.w = f2bf(v.w);
  ((ushort4*)Wb)[idx] = o;
}

// W_dec (D,H) -> WTb (H,D) in bf16 (halves decode gather traffic; err ~1e-3 << 0.16)
__global__ __launch_bounds__(256) void transpose_wdec_bf16(const float* __restrict__ Wd,
                                                           unsigned short* __restrict__ WTb) {
  __shared__ float tile[32][33];
  const int bx = blockIdx.x * 32;  // h
  const int by = blockIdx.y * 32;  // d
  const int tx = threadIdx.x;      // 0..31
  const int ty = threadIdx.y;      // 0..7
#pragma unroll
  for (int i = 0; i < 32; i += 8)
    tile[ty + i][tx] = Wd[(size_t)(by + ty + i) * H_ + bx + tx];
  __syncthreads();
#pragma unroll
  for (int i = 0; i < 32; i += 8)
    WTb[(size_t)(bx + ty + i) * D_ + by + tx] = f2bf(tile[tx][ty + i]);
}

// ---------------- bf16 MFMA encode GEMM + fused candidate extraction --------
__device__ __forceinline__ void async16(const unsigned short* g, unsigned short* l) {
  __builtin_amdgcn_global_load_lds(
      (const __attribute__((address_space(1))) unsigned int*)(const void*)g,
      (__attribute__((address_space(3))) unsigned int*)(void*)l, 16, 0, 0);
}

__global__ __launch_bounds__(256) void encode_mfma(const unsigned short* __restrict__ Xb,
                                                   const unsigned short* __restrict__ Wb,
                                                   const float* __restrict__ benc,
                                                   unsigned short* __restrict__ preb,
                                                   float* __restrict__ candV,
                                                   int* __restrict__ candI,
                                                   int* __restrict__ cnt) {
  __shared__ __align__(16) unsigned short As[128 * 32];
  __shared__ __align__(16) unsigned short Bs[128 * 32];
  const int t = threadIdx.x;
  const int w = t >> 6, l = t & 63;
  const int wm = w >> 1, wn = w & 1;
  const int bm = blockIdx.x * 128, bn = blockIdx.y * 128;

  f32x4 acc[4][4];
#pragma unroll
  for (int i = 0; i < 4; i++)
#pragma unroll
    for (int j = 0; j < 4; j++) acc[i][j] = (f32x4){0.f, 0.f, 0.f, 0.f};

  const int r0 = t >> 2, kc0 = (t & 3) * 8;
  const unsigned short* ga0 = Xb + (size_t)(bm + r0) * D_ + kc0;
  const unsigned short* ga1 = Xb + (size_t)(bm + r0 + 64) * D_ + kc0;
  const unsigned short* gb0 = Wb + (size_t)(bn + r0) * D_ + kc0;
  const unsigned short* gb1 = Wb + (size_t)(bn + r0 + 64) * D_ + kc0;
  unsigned short* la0 = &As[t * 8];
  unsigned short* la1 = &As[(t + 256) * 8];
  unsigned short* lb0 = &Bs[t * 8];
  unsigned short* lb1 = &Bs[(t + 256) * 8];

  const int am = l & 15;
  const int aq = l >> 4;
  const int aoff = aq * 8;

  for (int k0 = 0; k0 < D_; k0 += 32) {
    async16(ga0 + k0, la0);
    async16(ga1 + k0, la1);
    async16(gb0 + k0, lb0);
    async16(gb1 + k0, lb1);
    __syncthreads();
    bf16x8 a[4], b[4];
#pragma unroll
    for (int i = 0; i < 4; i++)
      a[i] = *(const bf16x8*)&As[(wm * 64 + i * 16 + am) * 32 + aoff];
#pragma unroll
    for (int j = 0; j < 4; j++)
      b[j] = *(const bf16x8*)&Bs[(wn * 64 + j * 16 + am) * 32 + aoff];
#pragma unroll
    for (int i = 0; i < 4; i++)
#pragma unroll
      for (int j = 0; j < 4; j++)
        acc[i][j] = __builtin_amdgcn_mfma_f32_16x16x32_bf16(a[i], b[j], acc[i][j], 0, 0, 0);
    __syncthreads();
  }

  // epilogue: C/D layout col=lane&15, row=(lane>>4)*4+reg [m89/m91].
  // write bf16 pre (fallback food) + append candidates >= T0 to per-row lists.
  float bias[4];
#pragma unroll
  for (int j = 0; j < 4; j++) bias[j] = benc[bn + wn * 64 + j * 16 + am];
#pragma unroll
  for (int i = 0; i < 4; i++)
#pragma unroll
    for (int r = 0; r < 4; r++) {
      const int row = bm + wm * 64 + i * 16 + aq * 4 + r;
      unsigned short* orow = preb + (size_t)row * H_ + bn + wn * 64 + am;
#pragma unroll
      for (int j = 0; j < 4; j++) {
        const float val = acc[i][j][r] + bias[j];
        orow[j * 16] = f2bf(val);
        if (val >= T0) {
          const int pos = atomicAdd(&cnt[row], 1);
          if (pos < CAP) {
            candV[(size_t)row * CAP + pos] = val;
            candI[(size_t)row * CAP + pos] = bn + wn * 64 + j * 16 + am;
          }
        }
      }
    }
}

// ---------------- topk: candidate-based top-32 + fp64 boundary refinement ---
__global__ __launch_bounds__(256) void topk_kernel(const float* __restrict__ candV,
                                                   const int* __restrict__ candI,
                                                   const int* __restrict__ cnt,
                                                   const unsigned short* __restrict__ preb,
                                                   const float* __restrict__ x,
                                                   const float* __restrict__ W,
                                                   const float* __restrict__ benc,
                                                   const float* __restrict__ bdec,
                                                   float* __restrict__ ovals,
                                                   int* __restrict__ oidx,
                                                   const float delta2) {
  const int row = blockIdx.x;
  const int t = threadIdx.x;

  __shared__ int si4[4];
  __shared__ float sf4[4];
  __shared__ double sd4[4];
  __shared__ float cv[NC];
  __shared__ int ci[NC];
  __shared__ float rv[NC];
  __shared__ int ri[NC];
  __shared__ int scnt;
  __shared__ int rl[24];
  __shared__ int nrl;

  const int cntRaw = cnt[row];
  const int m0 = (cntRaw < CAP) ? cntRaw : CAP;
  const bool fallback = (cntRaw > CAP) || (m0 < 33);  // statistically never

  if (t == 0) scnt = 0;
  __syncthreads();

  if (!fallback) {
    // load candidates (<= CAP = 4 per thread)
    float cVr[4];
    int cIr[4];
#pragma unroll
    for (int k = 0; k < 4; k++) {
      const int c = t + k * 256;
      const bool ok = c < m0;
      cVr[k] = ok ? candV[(size_t)row * CAP + c] : -1e30f;
      cIr[k] = ok ? candI[(size_t)row * CAP + c] : 0;
    }
    float T = -1e30f;
    if (m0 > NC) {
      // bisect threshold so count(>=T) in [48, NC]; window ~0.5 wide -> converges
      float tmax = fmaxf(fmaxf(cVr[0], cVr[1]), fmaxf(cVr[2], cVr[3]));
      const float gmax = blockMaxF(tmax, sf4, t);
      float lo = T0, hi = gmax + 1.0f;
      T = lo;
      for (int it = 0; it < 40; ++it) {
        const float mid = 0.5f * (lo + hi);
        int c = 0;
#pragma unroll
        for (int k = 0; k < 4; k++) c += (cVr[k] >= mid) ? 1 : 0;
        c = blockSumI(c, si4, t);
        if (c >= 48 && c <= NC) { T = mid; break; }
        if (c < 48) hi = mid;
        else { lo = mid; T = mid; }
      }
    }
#pragma unroll
    for (int k = 0; k < 4; k++) {
      if (cVr[k] >= T && (t + k * 256) < m0) {
        const int pos = atomicAdd(&scnt, 1);
        if (pos < NC) {
          cv[pos] = cVr[k];
          ci[pos] = cIr[k];
        }
      }
    }
    __syncthreads();
  } else {
    // fallback: full scan of the bf16 pre row (deterministic safety net)
    const ushort4* pr4 = (const ushort4*)(preb + (size_t)row * H_);
    float v[48];
#pragma unroll
    for (int i = 0; i < 12; i++) {
      const ushort4 q = pr4[i * 256 + t];
      v[i * 4 + 0] = bf2f(q.x);
      v[i * 4 + 1] = bf2f(q.y);
      v[i * 4 + 2] = bf2f(q.z);
      v[i * 4 + 3] = bf2f(q.w);
    }
    float tmin = v[0], tmax = v[0];
#pragma unroll
    for (int i = 1; i < 48; i++) {
      tmin = fminf(tmin, v[i]);
      tmax = fmaxf(tmax, v[i]);
    }
    const float gmin = blockMinF(tmin, sf4, t);
    const float gmax = blockMaxF(tmax, sf4, t);
    float lo = gmin - 1.0f, hi = gmax + 1.0f, T = lo;
    for (int it = 0; it < 40; ++it) {
      const float mid = 0.5f * (lo + hi);
      int c = 0;
#pragma unroll
      for (int i = 0; i < 48; i++) c += (v[i] >= mid) ? 1 : 0;
      c = blockSumI(c, si4, t);
      if (c >= 48 && c <= NC) { T = mid; break; }
      if (c < 48) hi = mid;
      else { lo = mid; T = mid; }
    }
#pragma unroll
    for (int i = 0; i < 12; i++)
#pragma unroll
      for (int j = 0; j < 4; j++) {
        if (v[i * 4 + j] >= T) {
          const int pos = atomicAdd(&scnt, 1);
          if (pos < NC) {
            cv[pos] = v[i * 4 + j];
            ci[pos] = (i * 256 + t) * 4 + j;
          }
        }
      }
    __syncthreads();
  }

  int m = scnt;
  if (m > NC) m = NC;

  // rank 1 (descending, tie-break by index)
  if (t < m) {
    const float vi = cv[t];
    const int ii = ci[t];
    int r = 0;
    for (int j = 0; j < m; j++) {
      const float vj = cv[j];
      r += (vj > vi || (vj == vi && ci[j] < ii)) ? 1 : 0;
    }
    rv[r] = vi;
    ri[r] = ii;
  }
  __syncthreads();

  // fp64 refinement of candidates within delta2 of the 31/32 boundary
  if (t == 0) nrl = 0;
  __syncthreads();
  if (m >= 33 && t < m) {
    const float v31 = rv[31], v32 = rv[32];
    const float myv = rv[t];
    const bool band = (t <= 31) ? (myv < v32 + delta2) : (myv > v31 - delta2);
    if (band) {
      const int q = atomicAdd(&nrl, 1);
      if (q < 24) rl[q] = t;
    }
  }
  __syncthreads();
  int nr = nrl;
  if (nr > 24) nr = 24;
  for (int c = 0; c < nr; ++c) {
    const int r = rl[c];
    const int hidx = ri[r];
    const float* wrow = W + (size_t)hidx * D_;
    const float* xrow = x + (size_t)row * D_;
    double s = 0.0;
    for (int d = t; d < D_; d += 256)
      s += (double)(xrow[d] - bdec[d]) * (double)wrow[d];
    s = blockSumD(s, sd4, t);
    if (t == 0) rv[r] = (float)(s + (double)benc[hidx]);
    __syncthreads();
  }

  // rank 2 (post-refinement)
  if (t < m) {
    const float vi = rv[t];
    const int ii = ri[t];
    int r = 0;
    for (int j = 0; j < m; j++) {
      const float vj = rv[j];
      r += (vj > vi || (vj == vi && ri[j] < ii)) ? 1 : 0;
    }
    cv[r] = vi;
    ci[r] = ii;
  }
  __syncthreads();

  if (t < K_) {
    float val = 0.f;
    int id = 0;
    if (t < m) {
      id = ci[t];
      val = fmaxf(cv[t], 0.f);
    }
    ovals[(size_t)row * K_ + t] = val;
    oidx[(size_t)row * K_ + t] = id;
  }
}

// ------- fused: zero sparse row + scatter top-32 + decode x_hat row ---------
__global__ __launch_bounds__(256) void decode_scatter(const float* __restrict__ vals,
                                                      const int* __restrict__ idxs,
                                                      const unsigned short* __restrict__ WTb,
                                                      const float* __restrict__ bdec,
                                                      float* __restrict__ S,
                                                      float* __restrict__ xhat) {
  const int row = blockIdx.x;
  const int t = threadIdx.x;
  __shared__ float sv[K_];
  __shared__ int si[K_];
  if (t < K_) {
    sv[t] = vals[(size_t)row * K_ + t];
    si[t] = idxs[(size_t)row * K_ + t];
  }
  float* srow = S + (size_t)row * H_;
  float4* s4 = (float4*)srow;
  const float4 z = make_float4(0.f, 0.f, 0.f, 0.f);
#pragma unroll
  for (int i = 0; i < 12; i++) s4[i * 256 + t] = z;
  __syncthreads();
  if (t < K_) srow[si[t]] = sv[t];

  float acc[6];
#pragma unroll
  for (int j = 0; j < 6; j++) acc[j] = bdec[t + j * 256];
  for (int k = 0; k < K_; k++) {
    const float vv = sv[k];
    if (vv == 0.f) continue;  // block-uniform
    const unsigned short* wr = WTb + (size_t)si[k] * D_;
#pragma unroll
    for (int j = 0; j < 6; j++) acc[j] = fmaf(vv, bf2f(wr[t + j * 256]), acc[j]);
  }
  float* orow = xhat + (size_t)row * D_;
#pragma unroll
  for (int j = 0; j < 6; j++) orow[t + j * 256] = acc[j];
}

// ---------------- launch ----------------------------------------------------
extern "C" void kernel_launch(void* const* d_in, const int* in_sizes, int n_in,
                              void* d_out, int out_size, void* d_ws, size_t ws_size,
                              hipStream_t stream) {
  const float* x = (const float*)d_in[0];
  const float* Wenc = (const float*)d_in[1];
  const float* benc = (const float*)d_in[2];
  const float* Wdec = (const float*)d_in[3];
  const float* bdec = (const float*)d_in[4];

  float* out = (float*)d_out;
  float* xhat = out;                   // output 0: (B, D)
  float* S = out + (size_t)B_ * D_;    // output 1: (B, H) sparse

  // scratch inside the (not-yet-needed) sparse output region:
  //   candV (B*CAP f32, 67MB) | candI (B*CAP i32, 67MB) | preb (B*H bf16, 403MB)
  float* candV = S;
  int* candI = (int*)(S + (size_t)B_ * CAP);
  unsigned short* preb = (unsigned short*)(S + (size_t)2 * B_ * CAP);

  // ws: WTb (H*D bf16) | Xb (B*D bf16) | Wb (H*D bf16) | vals | idxs | cnt  ~130MB
  char* wsc = (char*)d_ws;
  unsigned short* WTb = (unsigned short*)wsc;
  unsigned short* Xb = (unsigned short*)(wsc + (size_t)H_ * D_ * 2);
  unsigned short* Wb = (unsigned short*)(wsc + (size_t)H_ * D_ * 2 + (size_t)B_ * D_ * 2);
  float* vals = (float*)(wsc + (size_t)H_ * D_ * 4 + (size_t)B_ * D_ * 2);
  int* idxs = (int*)(vals + (size_t)B_ * K_);
  int* cnt = (int*)(idxs + (size_t)B_ * K_);

  zero_cnt<<<B_ / 256, 256, 0, stream>>>(cnt);
  transpose_wdec_bf16<<<dim3(H_ / 32, D_ / 32), dim3(32, 8), 0, stream>>>(Wdec, WTb);
  convert_x<<<(B_ * D_ / 4) / 256, 256, 0, stream>>>(x, bdec, Xb);
  convert_w<<<(H_ * D_ / 4) / 256, 256, 0, stream>>>(Wenc, Wb);
  encode_mfma<<<dim3(B_ / 128, H_ / 128), 256, 0, stream>>>(Xb, Wb, benc, preb, candV, candI, cnt);
  topk_kernel<<<B_, 256, 0, stream>>>(candV, candI, cnt, preb, x, Wenc, benc, bdec,
                                      vals, idxs, 0.04f);
  decode_scatter<<<B_, 256, 0, stream>>>(vals, idxs, WTb, bdec, S, xhat);
}